// Round 1
// baseline (178.240 us; speedup 1.0000x reference)
//
#include <hip/hip_runtime.h>
#include <math.h>

#define N_ROWS 4096
#define D_DIM  256
#define INV_T  (1.0f / 0.07f)

typedef _Float16 half8 __attribute__((ext_vector_type(8)));
typedef _Float16 half4 __attribute__((ext_vector_type(4)));
typedef float    f32x4 __attribute__((ext_vector_type(4)));

#define GLOAD_LDS(gp, lp) \
    __builtin_amdgcn_global_load_lds( \
        (const __attribute__((address_space(1))) void*)(gp), \
        (__attribute__((address_space(3))) void*)(lp), 16, 0, 0)

// ---------------------------------------------------------------------------
// K1: row-normalize features -> fp16 (one wave per row) + zero accum.
// ---------------------------------------------------------------------------
__global__ __launch_bounds__(256) void normalize_k(const float* __restrict__ f,
                                                   _Float16* __restrict__ fnh,
                                                   float* __restrict__ accum) {
    const int t   = threadIdx.x;
    const int gid = blockIdx.x * 256 + t;
    if (gid < 3 * N_ROWS) accum[gid] = 0.0f;

    const int lane = t & 63;
    const int row  = blockIdx.x * 4 + (t >> 6);
    float4 v = ((const float4*)(f + (size_t)row * D_DIM))[lane];
    float s = v.x * v.x + v.y * v.y + v.z * v.z + v.w * v.w;
    #pragma unroll
    for (int off = 32; off > 0; off >>= 1) s += __shfl_xor(s, off, 64);
    float rn = 1.0f / fmaxf(sqrtf(s), 1e-8f);
    half4 h;
    h.x = (_Float16)(v.x * rn);
    h.y = (_Float16)(v.y * rn);
    h.z = (_Float16)(v.z * rn);
    h.w = (_Float16)(v.w * rn);
    *(half4*)(fnh + (size_t)row * D_DIM + lane * 4) = h;
}

// ---------------------------------------------------------------------------
// K2: fused MFMA cosim + LDS cs round-trip + coalesced mask streaming.
// Round 9: unchanged resubmission of the verified round-8 kernel (175.7 us)
// -- previous bench attempt failed on infrastructure; re-establishing the
// baseline timing + rocprof counters before the next structural change.
// Internals: XOR-swizzled LDS via global_load_lds (0 conflicts), swapped
// MFMA operands (i on l15 side), cs->LDS fp16, mask reads 256 B-contiguous
// per row-segment, 64x64 tiles (4096 blocks, 16 KB LDS).
// ---------------------------------------------------------------------------
__global__ __launch_bounds__(256) void fused_k(const _Float16* __restrict__ fnh,
                                               const float* __restrict__ pm,
                                               const float* __restrict__ nm,
                                               float* __restrict__ accum) {
    __shared__ __align__(16) _Float16 lds[64 * 128];   // 16 KB
    _Float16* As = lds;             // [64][64] halfs during K-loop
    _Float16* Bs = lds + 64 * 64;   // [64][64] halfs during K-loop
    // cs (post-K-loop) reuses lds[0..4096): row*128 B, 16B-granule swizzle.

    const int t    = threadIdx.x;
    const int lane = t & 63;
    const int w    = t >> 6;        // wave 0..3
    const int wr   = w >> 1;        // i-half of tile
    const int wc   = w & 1;         // j-half of tile
    const int i0   = blockIdx.y * 64;
    const int j0   = blockIdx.x * 64;
    const int l15  = lane & 15;
    const int grp  = lane >> 4;

    // staging: 8 lanes-worth of granules per row, XOR-swizzled
    const int srow = t >> 3;                          // 0..31 per issue
    const int sslot = ((t & 7) ^ ((t >> 3) & 7)) * 8; // swizzled 16B granule (halfs)

    f32x4 acc[2][2];  // [jt][it]
    #pragma unroll
    for (int a = 0; a < 2; ++a)
        #pragma unroll
        for (int b = 0; b < 2; ++b)
            acc[a][b] = (f32x4){0.f, 0.f, 0.f, 0.f};

    for (int k0 = 0; k0 < D_DIM; k0 += 64) {
        #pragma unroll
        for (int q = 0; q < 2; ++q) {
            GLOAD_LDS(fnh + (size_t)(i0 + q * 32 + srow) * D_DIM + k0 + sslot,
                      &As[q * 2048 + w * 512]);
            GLOAD_LDS(fnh + (size_t)(j0 + q * 32 + srow) * D_DIM + k0 + sslot,
                      &Bs[q * 2048 + w * 512]);
        }
        __syncthreads();

        #pragma unroll
        for (int kk = 0; kk < 2; ++kk) {
            half8 aj[2], bi[2];
            #pragma unroll
            for (int jt = 0; jt < 2; ++jt) {
                const int r = wc * 32 + jt * 16 + l15;
                aj[jt] = *(const half8*)&Bs[r * 64 + (((kk * 4 + grp) ^ (r & 7)) << 3)];
            }
            #pragma unroll
            for (int it = 0; it < 2; ++it) {
                const int r = wr * 32 + it * 16 + l15;
                bi[it] = *(const half8*)&As[r * 64 + (((kk * 4 + grp) ^ (r & 7)) << 3)];
            }
            #pragma unroll
            for (int jt = 0; jt < 2; ++jt)
                #pragma unroll
                for (int it = 0; it < 2; ++it)
                    acc[jt][it] = __builtin_amdgcn_mfma_f32_16x16x32_f16(
                        aj[jt], bi[it], acc[jt][it], 0, 0, 0);
        }
        __syncthreads();
    }

    // cs -> LDS as fp16. (i_loc = wr*32+it*16+l15, j_loc = wc*32+jt*16+grp*4+reg)
    // Row = 128 B = 8 granules of 16 B; granule g stored at slot g^(row&7).
    #pragma unroll
    for (int it = 0; it < 2; ++it) {
        const int row = wr * 32 + it * 16 + l15;
        #pragma unroll
        for (int jt = 0; jt < 2; ++jt) {
            half4 h;
            h.x = (_Float16)(acc[jt][it][0] * INV_T);
            h.y = (_Float16)(acc[jt][it][1] * INV_T);
            h.z = (_Float16)(acc[jt][it][2] * INV_T);
            h.w = (_Float16)(acc[jt][it][3] * INV_T);
            const int g   = wc * 4 + jt * 2 + (grp >> 1);
            const int off = ((g ^ (row & 7)) << 4) | ((grp & 1) << 3);
            *(half4*)((char*)lds + row * 128 + off) = h;
        }
    }
    __syncthreads();

    // Mask streaming: step s covers rows s*16+lrow (lrow = t>>4), 16 lanes/row
    // each loading float4 -> 256 B contiguous per row-segment.
    const int lrow = t >> 4;   // 0..15
    const int lcol = t & 15;
    #pragma unroll
    for (int s = 0; s < 4; ++s) {
        const int r  = s * 16 + lrow;
        const int i  = i0 + r;
        const int jb = j0 + lcol * 4;
        float4 pmv = *(const float4*)(pm + (size_t)i * N_ROWS + jb);
        float4 nmv = *(const float4*)(nm + (size_t)i * N_ROWS + jb);
        half4 h = *(const half4*)((const char*)lds + r * 128 +
                                  ((((lcol >> 1) ^ (r & 7)) << 4) | ((lcol & 1) << 3)));
        float cse[4] = {(float)h.x, (float)h.y, (float)h.z, (float)h.w};
        float pme[4] = {pmv.x, pmv.y, pmv.z, pmv.w};
        float nme[4] = {nmv.x, nmv.y, nmv.z, nmv.w};
        float negp = 0.f, posp = 0.f, np = 0.f;
        #pragma unroll
        for (int e = 0; e < 4; ++e) {
            float keep = (i == jb + e) ? 0.f : 1.f;
            float p  = pme[e] * keep;
            float nv = nme[e] * keep;
            negp = fmaf(__expf(cse[e]), nv, negp);
            posp = fmaf(cse[e], p, posp);
            np  += p;
        }
        #pragma unroll
        for (int off = 1; off < 16; off <<= 1) {
            negp += __shfl_xor(negp, off, 64);
            posp += __shfl_xor(posp, off, 64);
            np   += __shfl_xor(np,   off, 64);
        }
        if (lcol == 0) {
            atomicAdd(&accum[i], negp);
            atomicAdd(&accum[N_ROWS + i], posp);
            atomicAdd(&accum[2 * N_ROWS + i], np);
        }
    }
}

// ---------------------------------------------------------------------------
// K3: final reduction over rows -> scalar loss
// ---------------------------------------------------------------------------
__global__ __launch_bounds__(256) void final_k(const float* __restrict__ accum,
                                               float* __restrict__ out) {
    const int t = threadIdx.x;
    float s = 0.f;
    for (int i = t; i < N_ROWS; i += 256) {
        float neg  = accum[i];
        float posc = accum[N_ROWS + i];
        float np   = accum[2 * N_ROWS + i];
        float term = (np > 0.f) ? (posc - np * logf(fmaxf(neg, 1e-30f))) / np : 0.f;
        s += term;
    }
    #pragma unroll
    for (int off = 32; off > 0; off >>= 1) s += __shfl_xor(s, off, 64);
    __shared__ float wsum[4];
    if ((t & 63) == 0) wsum[t >> 6] = s;
    __syncthreads();
    if (t == 0) {
        float tot = wsum[0] + wsum[1] + wsum[2] + wsum[3];
        out[0] = -tot / (float)N_ROWS;
    }
}

// ---------------------------------------------------------------------------
extern "C" void kernel_launch(void* const* d_in, const int* in_sizes, int n_in,
                              void* d_out, int out_size, void* d_ws, size_t ws_size,
                              hipStream_t stream) {
    const float* feat = (const float*)d_in[0];
    const float* pm   = (const float*)d_in[1];
    const float* nm   = (const float*)d_in[2];
    float* out = (float*)d_out;

    _Float16* fnh = (_Float16*)d_ws;                          // 2 MB
    float* accum  = (float*)(fnh + (size_t)N_ROWS * D_DIM);   // 48 KB

    normalize_k<<<N_ROWS / 4, 256, 0, stream>>>(feat, fnh, accum);

    dim3 grid(N_ROWS / 64, N_ROWS / 64);
    fused_k<<<grid, 256, 0, stream>>>(fnh, pm, nm, accum);

    final_k<<<1, 256, 0, stream>>>(accum, out);
}

// Round 2
// 173.062 us; speedup vs baseline: 1.0299x; 1.0299x over previous
//
#include <hip/hip_runtime.h>
#include <math.h>

#define N_ROWS 4096
#define D_DIM  256
#define INV_T  (1.0f / 0.07f)

typedef _Float16 half8 __attribute__((ext_vector_type(8)));
typedef _Float16 half4 __attribute__((ext_vector_type(4)));
typedef float    f32x4 __attribute__((ext_vector_type(4)));

#define GLOAD_LDS(gp, lp) \
    __builtin_amdgcn_global_load_lds( \
        (const __attribute__((address_space(1))) void*)(gp), \
        (__attribute__((address_space(3))) void*)(lp), 16, 0, 0)

// ---------------------------------------------------------------------------
// K1: row-normalize features -> fp16 (one wave per row) + zero accum.
// ---------------------------------------------------------------------------
__global__ __launch_bounds__(256) void normalize_k(const float* __restrict__ f,
                                                   _Float16* __restrict__ fnh,
                                                   float* __restrict__ accum) {
    const int t   = threadIdx.x;
    const int gid = blockIdx.x * 256 + t;
    if (gid < 3 * N_ROWS) accum[gid] = 0.0f;

    const int lane = t & 63;
    const int row  = blockIdx.x * 4 + (t >> 6);
    float4 v = ((const float4*)(f + (size_t)row * D_DIM))[lane];
    float s = v.x * v.x + v.y * v.y + v.z * v.z + v.w * v.w;
    #pragma unroll
    for (int off = 32; off > 0; off >>= 1) s += __shfl_xor(s, off, 64);
    float rn = 1.0f / fmaxf(sqrtf(s), 1e-8f);
    half4 h;
    h.x = (_Float16)(v.x * rn);
    h.y = (_Float16)(v.y * rn);
    h.z = (_Float16)(v.z * rn);
    h.w = (_Float16)(v.w * rn);
    *(half4*)(fnh + (size_t)row * D_DIM + lane * 4) = h;
}

// ---------------------------------------------------------------------------
// K2, round 2 of this session.
// Theory: round-8 kernel (61.5 us) was phase-serialized -- mask loads only
// in flight during the short post-GEMM tail -> effective mask BW 2.1 TB/s.
// Changes:
//  (1) Mask loads issued in REGISTERS at block start; the K-loop's first
//      __syncthreads (vmcnt(0) drain) doubles as their wait. Latency rides
//      under the whole GEMM phase. Compressed to 2 bitmask VGPRs right
//      after the first barrier (diag i==j folded in) to keep peak VGPR<=64.
//  (2) No cs->LDS round trip: acc fragments consumed in registers.
//      Mask addressing follows the MFMA fragment layout:
//      i = i0+wr*32+it*16+l15, j = j0+wc*32+jt*16+grp*4+reg.
//  (3) Row-reduce is a 2-step butterfly over grp (12 shuffles vs 48),
//      then 16-lane-wide atomics.
// GEMM internals (XOR-swizzled LDS via global_load_lds, swapped operands)
// are verbatim from the verified round-8 kernel.
// ---------------------------------------------------------------------------
__global__ __launch_bounds__(256) void fused_k(const _Float16* __restrict__ fnh,
                                               const float* __restrict__ pm,
                                               const float* __restrict__ nm,
                                               float* __restrict__ accum) {
    __shared__ __align__(16) _Float16 lds[64 * 128];   // 16 KB
    _Float16* As = lds;             // [64][64] halfs during K-loop
    _Float16* Bs = lds + 64 * 64;   // [64][64] halfs during K-loop

    const int t    = threadIdx.x;
    const int lane = t & 63;
    const int w    = t >> 6;        // wave 0..3
    const int wr   = w >> 1;        // i-half of tile
    const int wc   = w & 1;         // j-half of tile
    const int i0   = blockIdx.y * 64;
    const int j0   = blockIdx.x * 64;
    const int l15  = lane & 15;
    const int grp  = lane >> 4;

    // staging: 8 lanes-worth of granules per row, XOR-swizzled
    const int srow = t >> 3;                          // 0..31 per issue
    const int sslot = ((t & 7) ^ ((t >> 3) & 7)) * 8; // swizzled 16B granule (halfs)

    // ---- (1) mask prefetch: 8 float4 loads, in flight during whole GEMM ----
    const int mrow0 = i0 + wr * 32 + l15;
    const int mcol0 = j0 + wc * 32 + grp * 4;
    float4 pmv[2][2], nmv[2][2];
    #pragma unroll
    for (int it = 0; it < 2; ++it)
        #pragma unroll
        for (int jt = 0; jt < 2; ++jt) {
            const size_t off = (size_t)(mrow0 + it * 16) * N_ROWS + (mcol0 + jt * 16);
            pmv[it][jt] = *(const float4*)(pm + off);
            nmv[it][jt] = *(const float4*)(nm + off);
        }

    f32x4 acc[2][2];  // [jt][it]
    #pragma unroll
    for (int a = 0; a < 2; ++a)
        #pragma unroll
        for (int b = 0; b < 2; ++b)
            acc[a][b] = (f32x4){0.f, 0.f, 0.f, 0.f};

    unsigned pmb = 0, nmb = 0;   // 16 bits each: b = it*8 + jt*4 + e

    #pragma unroll
    for (int k0 = 0; k0 < D_DIM; k0 += 64) {
        #pragma unroll
        for (int q = 0; q < 2; ++q) {
            GLOAD_LDS(fnh + (size_t)(i0 + q * 32 + srow) * D_DIM + k0 + sslot,
                      &As[q * 2048 + w * 512]);
            GLOAD_LDS(fnh + (size_t)(j0 + q * 32 + srow) * D_DIM + k0 + sslot,
                      &Bs[q * 2048 + w * 512]);
        }
        __syncthreads();   // drains staging AND (first iter) the mask loads

        if (k0 == 0) {
            // ---- compress masks to bits; diagonal (i==j) cleared here ----
            #pragma unroll
            for (int it = 0; it < 2; ++it)
                #pragma unroll
                for (int jt = 0; jt < 2; ++jt) {
                    const int i = mrow0 + it * 16;
                    const int jb = mcol0 + jt * 16;
                    float pe[4] = {pmv[it][jt].x, pmv[it][jt].y,
                                   pmv[it][jt].z, pmv[it][jt].w};
                    float ne[4] = {nmv[it][jt].x, nmv[it][jt].y,
                                   nmv[it][jt].z, nmv[it][jt].w};
                    #pragma unroll
                    for (int e = 0; e < 4; ++e) {
                        const int b = it * 8 + jt * 4 + e;
                        const unsigned keep = (unsigned)(i != (jb + e));
                        pmb |= (((unsigned)(pe[e] != 0.f) & keep) << b);
                        nmb |= (((unsigned)(ne[e] != 0.f) & keep) << b);
                    }
                }
        }

        #pragma unroll
        for (int kk = 0; kk < 2; ++kk) {
            half8 aj[2], bi[2];
            #pragma unroll
            for (int jt = 0; jt < 2; ++jt) {
                const int r = wc * 32 + jt * 16 + l15;
                aj[jt] = *(const half8*)&Bs[r * 64 + (((kk * 4 + grp) ^ (r & 7)) << 3)];
            }
            #pragma unroll
            for (int it = 0; it < 2; ++it) {
                const int r = wr * 32 + it * 16 + l15;
                bi[it] = *(const half8*)&As[r * 64 + (((kk * 4 + grp) ^ (r & 7)) << 3)];
            }
            #pragma unroll
            for (int jt = 0; jt < 2; ++jt)
                #pragma unroll
                for (int it = 0; it < 2; ++it)
                    acc[jt][it] = __builtin_amdgcn_mfma_f32_16x16x32_f16(
                        aj[jt], bi[it], acc[jt][it], 0, 0, 0);
        }
        __syncthreads();
    }

    // ---- (2)+(3) streaming from registers, butterfly over grp, atomics ----
    #pragma unroll
    for (int it = 0; it < 2; ++it) {
        float negp = 0.f, posp = 0.f, np = 0.f;
        #pragma unroll
        for (int jt = 0; jt < 2; ++jt)
            #pragma unroll
            for (int e = 0; e < 4; ++e) {
                const int b = it * 8 + jt * 4 + e;
                const float cs = acc[jt][it][e] * INV_T;
                const float pf = (float)((pmb >> b) & 1u);
                const float nf = (float)((nmb >> b) & 1u);
                negp = fmaf(__expf(cs), nf, negp);
                posp = fmaf(cs, pf, posp);
                np  += pf;
            }
        #pragma unroll
        for (int off = 16; off < 64; off <<= 1) {
            negp += __shfl_xor(negp, off, 64);
            posp += __shfl_xor(posp, off, 64);
            np   += __shfl_xor(np,   off, 64);
        }
        if (grp == 0) {            // lanes 0..15: one row each
            const int i = mrow0 + it * 16;
            atomicAdd(&accum[i], negp);
            atomicAdd(&accum[N_ROWS + i], posp);
            atomicAdd(&accum[2 * N_ROWS + i], np);
        }
    }
}

// ---------------------------------------------------------------------------
// K3: final reduction over rows -> scalar loss
// ---------------------------------------------------------------------------
__global__ __launch_bounds__(256) void final_k(const float* __restrict__ accum,
                                               float* __restrict__ out) {
    const int t = threadIdx.x;
    float s = 0.f;
    for (int i = t; i < N_ROWS; i += 256) {
        float neg  = accum[i];
        float posc = accum[N_ROWS + i];
        float np   = accum[2 * N_ROWS + i];
        float term = (np > 0.f) ? (posc - np * logf(fmaxf(neg, 1e-30f))) / np : 0.f;
        s += term;
    }
    #pragma unroll
    for (int off = 32; off > 0; off >>= 1) s += __shfl_xor(s, off, 64);
    __shared__ float wsum[4];
    if ((t & 63) == 0) wsum[t >> 6] = s;
    __syncthreads();
    if (t == 0) {
        float tot = wsum[0] + wsum[1] + wsum[2] + wsum[3];
        out[0] = -tot / (float)N_ROWS;
    }
}

// ---------------------------------------------------------------------------
extern "C" void kernel_launch(void* const* d_in, const int* in_sizes, int n_in,
                              void* d_out, int out_size, void* d_ws, size_t ws_size,
                              hipStream_t stream) {
    const float* feat = (const float*)d_in[0];
    const float* pm   = (const float*)d_in[1];
    const float* nm   = (const float*)d_in[2];
    float* out = (float*)d_out;

    _Float16* fnh = (_Float16*)d_ws;                          // 2 MB
    float* accum  = (float*)(fnh + (size_t)N_ROWS * D_DIM);   // 48 KB

    normalize_k<<<N_ROWS / 4, 256, 0, stream>>>(feat, fnh, accum);

    dim3 grid(N_ROWS / 64, N_ROWS / 64);
    fused_k<<<grid, 256, 0, stream>>>(fnh, pm, nm, accum);

    final_k<<<1, 256, 0, stream>>>(accum, out);
}